// Round 8
// baseline (392.122 us; speedup 1.0000x reference)
//
#include <hip/hip_runtime.h>
#include <hip/hip_bf16.h>

// Problem constants (match reference setup_inputs)
#define NSETS 8
#define NPTS  4096
#define DF    16
#define KNN   16
#define QG    2                   // query groups per lane (Q=2)
#define QPB   (64 * QG)           // 128 queries per block
#define NWV   8                   // waves per block
#define BLK   512
#define TILE  512                 // candidates staged into LDS per tile
#define NTILE (NPTS / TILE)       // 8
#define WSLICE (TILE / NWV)       // 64 candidates per wave per tile
#define NEDGE (NSETS * NPTS * KNN)

// Round-8: r7 was LDS-pipe bound — 5 broadcast ds_reads per candidate served
// only 64 pairs (16B useful per b128, ~12cyc each on the per-CU pipe; 41k DS
// instr/CU ~= the whole 470k-cyc runtime). Q=2 queries/lane: same 5 reads now
// serve 128 pairs, and 2 independent fma chains/candidate double ILP.
#define RES      12               // reservoir slots/lane/group (8+GRP = 12)
#define FLUSH_AT 9                // flush when any lane cnt >= this
#define GRP      4                // candidates between flush checks

#define FEAT_B   (TILE * DF * 4)             // 32768 B: feat4[4][TILE] transposed
#define NRM_B    (TILE * 4)                  // 2048 B:  nrm_t[TILE]
#define RESV_OFF (FEAT_B + NRM_B)            // 34816
#define RESV_B   (QG * RES * BLK * 8)        // 98304 B
#define SMEM_B   (RESV_OFF + RESV_B)         // 133120 B -> 1 block/CU

__global__ __launch_bounds__(BLK, 2) void knn_kernel(const float* __restrict__ x,
                                                     float* __restrict__ out) {
    __shared__ float tau_sh[QPB];                 // shared per-query tau
    __shared__ __align__(16) char smem[SMEM_B];
    float4* feat4 = (float4*)smem;                // feat4[r*TILE + c], r=0..3
    float*  nrm_t = (float*)(smem + FEAT_B);      // candidate norms
    float2* resvA = (float2*)(smem + RESV_OFF);   // resvA[slot*BLK + t]
    float2* resvB = resvA + RES * BLK;
    // Post-scan overlay (96 KB <= SMEM_B): [distsA|distsB][idxA|idxB]
    float*          lds_d = (float*)smem;
    unsigned short* lds_i = (unsigned short*)(smem + QG * BLK * KNN * 4);

    const int t    = threadIdx.x;
    const int lane = t & 63;
    const int wv   = t >> 6;                    // wave 0..7
    const int set  = blockIdx.x >> 5;           // 32 blocks per set
    const int q0   = (blockIdx.x & 31) * QPB;
    const int qa   = q0 + lane;                 // group-A query
    const int qb   = q0 + 64 + lane;            // group-B query

    const float* xs = x + (size_t)set * NPTS * DF;

    if (t < QPB) tau_sh[t] = 3.0e38f;

    // Query features (both groups): q2 via the SAME pairwise tree as candidate
    // norms; qn = -2*q (exact pow2 scale commutes with fma rounding).
    float qnA[DF], qnB[DF];
    float q2A, q2B;
    {
        const float4* qp = (const float4*)(xs + (size_t)qa * DF);
        float4 a = qp[0], b = qp[1], g = qp[2], d = qp[3];
        float r0 = __fadd_rn(__fmul_rn(a.x, a.x), __fmul_rn(g.x, g.x));
        float r1 = __fadd_rn(__fmul_rn(a.y, a.y), __fmul_rn(g.y, g.y));
        float r2 = __fadd_rn(__fmul_rn(a.z, a.z), __fmul_rn(g.z, g.z));
        float r3 = __fadd_rn(__fmul_rn(a.w, a.w), __fmul_rn(g.w, g.w));
        float r4 = __fadd_rn(__fmul_rn(b.x, b.x), __fmul_rn(d.x, d.x));
        float r5 = __fadd_rn(__fmul_rn(b.y, b.y), __fmul_rn(d.y, d.y));
        float r6 = __fadd_rn(__fmul_rn(b.z, b.z), __fmul_rn(d.z, d.z));
        float r7 = __fadd_rn(__fmul_rn(b.w, b.w), __fmul_rn(d.w, d.w));
        q2A = __fadd_rn(__fadd_rn(__fadd_rn(r0, r1), __fadd_rn(r2, r3)),
                        __fadd_rn(__fadd_rn(r4, r5), __fadd_rn(r6, r7)));
        qnA[0]=a.x; qnA[1]=a.y; qnA[2]=a.z; qnA[3]=a.w;
        qnA[4]=b.x; qnA[5]=b.y; qnA[6]=b.z; qnA[7]=b.w;
        qnA[8]=g.x; qnA[9]=g.y; qnA[10]=g.z; qnA[11]=g.w;
        qnA[12]=d.x; qnA[13]=d.y; qnA[14]=d.z; qnA[15]=d.w;
    }
    {
        const float4* qp = (const float4*)(xs + (size_t)qb * DF);
        float4 a = qp[0], b = qp[1], g = qp[2], d = qp[3];
        float r0 = __fadd_rn(__fmul_rn(a.x, a.x), __fmul_rn(g.x, g.x));
        float r1 = __fadd_rn(__fmul_rn(a.y, a.y), __fmul_rn(g.y, g.y));
        float r2 = __fadd_rn(__fmul_rn(a.z, a.z), __fmul_rn(g.z, g.z));
        float r3 = __fadd_rn(__fmul_rn(a.w, a.w), __fmul_rn(g.w, g.w));
        float r4 = __fadd_rn(__fmul_rn(b.x, b.x), __fmul_rn(d.x, d.x));
        float r5 = __fadd_rn(__fmul_rn(b.y, b.y), __fmul_rn(d.y, d.y));
        float r6 = __fadd_rn(__fmul_rn(b.z, b.z), __fmul_rn(d.z, d.z));
        float r7 = __fadd_rn(__fmul_rn(b.w, b.w), __fmul_rn(d.w, d.w));
        q2B = __fadd_rn(__fadd_rn(__fadd_rn(r0, r1), __fadd_rn(r2, r3)),
                        __fadd_rn(__fadd_rn(r4, r5), __fadd_rn(r6, r7)));
        qnB[0]=a.x; qnB[1]=a.y; qnB[2]=a.z; qnB[3]=a.w;
        qnB[4]=b.x; qnB[5]=b.y; qnB[6]=b.z; qnB[7]=b.w;
        qnB[8]=g.x; qnB[9]=g.y; qnB[10]=g.z; qnB[11]=g.w;
        qnB[12]=d.x; qnB[13]=d.y; qnB[14]=d.z; qnB[15]=d.w;
    }
#pragma unroll
    for (int d2 = 0; d2 < DF; ++d2) { qnA[d2] = -2.0f * qnA[d2];
                                      qnB[d2] = -2.0f * qnB[d2]; }

    float LdA[KNN], LdB[KNN];
    int   LiA[KNN], LiB[KNN];
#pragma unroll
    for (int j = 0; j < KNN; ++j) { LdA[j] = 3.0e38f; LiA[j] = 0;
                                    LdB[j] = 3.0e38f; LiB[j] = 0; }
    int cntA = 0, cntB = 0;

    // Exact drain for one group: strict-< shift-insert in append (ascending
    // idx) order, then publish running 16th to that query's shared tau.
    auto flush1 = [&](float2* rb, float (&Ld)[KNN], int (&Li)[KNN],
                      int& cnt, int tidx) {
        for (int e = 0; e < RES; ++e) {
            if (!__any(e < cnt)) break;
            float2 en = rb[e * BLK + t];
            const float d  = (e < cnt) ? en.x : 3.0e38f;
            const int   ci = __float_as_int(en.y);
            if (d < Ld[KNN - 1]) {
#pragma unroll
                for (int j = KNN - 1; j >= 1; --j) {
                    const bool sh   = d < Ld[j - 1];
                    const bool here = d < Ld[j];
                    const float nd = sh ? Ld[j - 1] : (here ? d  : Ld[j]);
                    const int   ni = sh ? Li[j - 1] : (here ? ci : Li[j]);
                    Ld[j] = nd; Li[j] = ni;
                }
                if (d < Ld[0]) { Ld[0] = d; Li[0] = ci; }
            }
        }
        cnt = 0;
        volatile float* ts = (volatile float*)tau_sh;   // benign-race cons. min
        float cur = ts[tidx];
        ts[tidx] = fminf(cur, Ld[KNN - 1]);
    };

    for (int tile = 0; tile < NTILE; ++tile) {
        __syncthreads();   // previous tile fully consumed (covers tau init too)
        {
            const int c = tile * TILE + t;   // thread t stages one candidate
            const float4* p = (const float4*)(xs + (size_t)c * DF);
            float4 a = p[0], b = p[1], g = p[2], d = p[3];
            float r0 = __fadd_rn(__fmul_rn(a.x, a.x), __fmul_rn(g.x, g.x));
            float r1 = __fadd_rn(__fmul_rn(a.y, a.y), __fmul_rn(g.y, g.y));
            float r2 = __fadd_rn(__fmul_rn(a.z, a.z), __fmul_rn(g.z, g.z));
            float r3 = __fadd_rn(__fmul_rn(a.w, a.w), __fmul_rn(g.w, g.w));
            float r4 = __fadd_rn(__fmul_rn(b.x, b.x), __fmul_rn(d.x, d.x));
            float r5 = __fadd_rn(__fmul_rn(b.y, b.y), __fmul_rn(d.y, d.y));
            float r6 = __fadd_rn(__fmul_rn(b.z, b.z), __fmul_rn(d.z, d.z));
            float r7 = __fadd_rn(__fmul_rn(b.w, b.w), __fmul_rn(d.w, d.w));
            feat4[0 * TILE + t] = a;
            feat4[1 * TILE + t] = b;
            feat4[2 * TILE + t] = g;
            feat4[3 * TILE + t] = d;
            nrm_t[t] = __fadd_rn(
                __fadd_rn(__fadd_rn(r0, r1), __fadd_rn(r2, r3)),
                __fadd_rn(__fadd_rn(r4, r5), __fadd_rn(r6, r7)));
        }
        __syncthreads();

        const int lbase = wv * WSLICE;           // local slice base in tile
        const int gbase = tile * TILE + lbase;   // global candidate id base

        for (int g = 0; g < WSLICE; g += GRP) {
            const float tA = fminf(((volatile float*)tau_sh)[lane],
                                   LdA[KNN - 1]);
            const float tB = fminf(((volatile float*)tau_sh)[64 + lane],
                                   LdB[KNN - 1]);
#pragma unroll
            for (int u = 0; u < GRP; ++u) {
                const int lc = lbase + g + u;    // wave-uniform -> broadcast
                float4 f0 = feat4[0 * TILE + lc];
                float4 f1 = feat4[1 * TILE + lc];
                float4 f2 = feat4[2 * TILE + lc];
                float4 f3 = feat4[3 * TILE + lc];
                const float nc = nrm_t[lc];
                float dA = 0.f, dB = 0.f;
                dA = fmaf(qnA[0],  f0.x, dA); dB = fmaf(qnB[0],  f0.x, dB);
                dA = fmaf(qnA[1],  f0.y, dA); dB = fmaf(qnB[1],  f0.y, dB);
                dA = fmaf(qnA[2],  f0.z, dA); dB = fmaf(qnB[2],  f0.z, dB);
                dA = fmaf(qnA[3],  f0.w, dA); dB = fmaf(qnB[3],  f0.w, dB);
                dA = fmaf(qnA[4],  f1.x, dA); dB = fmaf(qnB[4],  f1.x, dB);
                dA = fmaf(qnA[5],  f1.y, dA); dB = fmaf(qnB[5],  f1.y, dB);
                dA = fmaf(qnA[6],  f1.z, dA); dB = fmaf(qnB[6],  f1.z, dB);
                dA = fmaf(qnA[7],  f1.w, dA); dB = fmaf(qnB[7],  f1.w, dB);
                dA = fmaf(qnA[8],  f2.x, dA); dB = fmaf(qnB[8],  f2.x, dB);
                dA = fmaf(qnA[9],  f2.y, dA); dB = fmaf(qnB[9],  f2.y, dB);
                dA = fmaf(qnA[10], f2.z, dA); dB = fmaf(qnB[10], f2.z, dB);
                dA = fmaf(qnA[11], f2.w, dA); dB = fmaf(qnB[11], f2.w, dB);
                dA = fmaf(qnA[12], f3.x, dA); dB = fmaf(qnB[12], f3.x, dB);
                dA = fmaf(qnA[13], f3.y, dA); dB = fmaf(qnB[13], f3.y, dB);
                dA = fmaf(qnA[14], f3.z, dA); dB = fmaf(qnB[14], f3.z, dB);
                dA = fmaf(qnA[15], f3.w, dA); dB = fmaf(qnB[15], f3.w, dB);
                const float distA = __fadd_rn(__fadd_rn(q2A, nc), dA);
                const float distB = __fadd_rn(__fadd_rn(q2B, nc), dB);
                const int ci = gbase + g + u;
                if (distA <= tA) {               // non-strict: keep boundary ties
                    resvA[cntA * BLK + t] = make_float2(distA, __int_as_float(ci));
                    ++cntA;
                }
                if (distB <= tB) {
                    resvB[cntB * BLK + t] = make_float2(distB, __int_as_float(ci));
                    ++cntB;
                }
            }
            if (__any((cntA >= FLUSH_AT) || (cntB >= FLUSH_AT))) {
                flush1(resvA, LdA, LiA, cntA, lane);
                flush1(resvB, LdB, LiB, cntB, 64 + lane);
            }
        }
    }
    flush1(resvA, LdA, LiA, cntA, lane);          // final drains
    flush1(resvB, LdB, LiB, cntB, 64 + lane);

    // ---- Merge the 8 per-wave lists per query and emit ---------------------
    __syncthreads();   // overlay aliases tile + reservoir regions
#pragma unroll
    for (int j = 0; j < KNN; ++j) {
        lds_d[t * KNN + j] = LdA[j];
        lds_d[BLK * KNN + t * KNN + j] = LdB[j];
        lds_i[t * KNN + j] = (unsigned short)LiA[j];
        lds_i[BLK * KNN + t * KNN + j] = (unsigned short)LiB[j];
    }
    __syncthreads();

    if (t < QPB) {
        const int l    = t;              // query index within block (0..127)
        const int grp  = l >> 6;         // 0 = A, 1 = B
        const int ln   = l & 63;
        const int gofs = grp * BLK * KNN;

        float h[NWV];
        int   hi[NWV];
        int   p[NWV];
#pragma unroll
        for (int w2 = 0; w2 < NWV; ++w2) {
            const int base = gofs + (w2 * 64 + ln) * KNN;
            p[w2]  = 0;
            h[w2]  = lds_d[base];
            hi[w2] = (int)lds_i[base];
        }

        const int    gq = set * NPTS + q0 + l;
        const size_t eb = (size_t)gq * KNN;
        float* osrc = out;
        float* odst = out + (size_t)NEDGE;
        float* odis = out + 2 * (size_t)NEDGE;
        const float srcf = (float)gq;

        for (int e = 0; e < KNN; ++e) {
            // (dist, idx) lexicographic min across 8 heads — exact stable
            // top-k order regardless of slice layout.
            float best = h[0];
            int   bi   = hi[0];
            int   bw   = 0;
#pragma unroll
            for (int w2 = 1; w2 < NWV; ++w2) {
                const bool better = (h[w2] < best) ||
                                    (h[w2] == best && hi[w2] < bi);
                if (better) { best = h[w2]; bi = hi[w2]; bw = w2; }
            }

#pragma unroll
            for (int w2 = 0; w2 < NWV; ++w2) {
                if (bw == w2) {
                    ++p[w2];
                    const int base = gofs + (w2 * 64 + ln) * KNN;
                    if (p[w2] < KNN) {
                        h[w2]  = lds_d[base + p[w2]];
                        hi[w2] = (int)lds_i[base + p[w2]];
                    } else {
                        h[w2]  = 3.0e38f;
                        hi[w2] = 0x7FFFFFFF;
                    }
                }
            }

            osrc[eb + e] = srcf;
            odst[eb + e] = (float)(set * NPTS + bi);
            odis[eb + e] = best;
        }
    }
}

// ---------------------------------------------------------------------------
extern "C" void kernel_launch(void* const* d_in, const int* in_sizes, int n_in,
                              void* d_out, int out_size, void* d_ws, size_t ws_size,
                              hipStream_t stream) {
    (void)in_sizes; (void)n_in; (void)out_size; (void)d_ws; (void)ws_size;
    const float* x = (const float*)d_in[0];  // (8, 4096, 16) f32
    float* out = (float*)d_out;              // [src|dst|dist] f32

    knn_kernel<<<NSETS * (NPTS / QPB), BLK, 0, stream>>>(x, out);
}